// Round 11
// baseline (130.743 us; speedup 1.0000x reference)
//
#include <hip/hip_runtime.h>
#include <hip/hip_bf16.h>

#define HID   64
#define BLOCK 320    // 4 consumer waves + 1 producer wave
#define GPB   8      // 64-token tiles per block -> 512 tokens/block -> 2048 blocks
#define NBUF  4      // buffer ring; producer lookahead 3

typedef short short8 __attribute__((ext_vector_type(8)));
typedef float floatx4 __attribute__((ext_vector_type(4)));

__device__ __forceinline__ short8 cvt8f(float4 f0, float4 f1) {
    union { __hip_bfloat162 h[4]; short8 s; } r;
    r.h[0] = __float22bfloat162_rn(make_float2(f0.x, f0.y));
    r.h[1] = __float22bfloat162_rn(make_float2(f0.z, f0.w));
    r.h[2] = __float22bfloat162_rn(make_float2(f1.x, f1.y));
    r.h[3] = __float22bfloat162_rn(make_float2(f1.z, f1.w));
    return r.s;
}

__device__ __forceinline__ void gload_lds16(const float* g, float* l) {
    __builtin_amdgcn_global_load_lds(
        (const __attribute__((address_space(1))) void*)g,
        (__attribute__((address_space(3))) void*)l, 16, 0, 0);
}

#define SB __builtin_amdgcn_sched_barrier(0)
#define WAITV(N) asm volatile("s_waitcnt vmcnt(" #N ")" ::: "memory")

// Producer stages the whole 16 KB tile (16 chunks). Consumption-order layout
// (rule 21: pre-swizzled global src, linear LDS dest): chunk c = mt*4+kc*2+hf
// holds, at 16B slot `lane`, x[orig + mt*16 + r15][kg*8 + kc*32 + hf*4 .. +4)
#define STAGE(g) do {                                                             \
    const long orig_ = blk0 + (g) * 64;                                           \
    _Pragma("unroll")                                                             \
    for (int c = 0; c < 16; ++c) {                                                \
        const int mt_ = c >> 2, kc_ = (c >> 1) & 1, hf_ = c & 1;                  \
        const float* src_ = x + (orig_ + mt_ * 16 + r15) * HID                    \
                              + kg * 8 + kc_ * 32 + hf_ * 4;                      \
        gload_lds16(src_, &sbuf[(g) & 3][c * 256]);                               \
    } } while (0)

// Consumer: mod for tile g's 4 token groups (issued one tile ahead of use).
#define MODL(g) do {                                                              \
    const long orig_ = blk0 + (g) * 64;                                           \
    _Pragma("unroll")                                                             \
    for (int mt = 0; mt < 4; ++mt)                                                \
        mv[g][mt] = mod[orig_ + mt * 16 + r15];                                   \
    } while (0)

// Consumer wave computes its 16 output cols (wave*16..) for all 64 tokens.
#define COMPUTE(g) do {                                                           \
    const long orig_ = blk0 + (g) * 64;                                           \
    _Pragma("unroll")                                                             \
    for (int mt = 0; mt < 4; ++mt) {                                              \
        const float4 q0 = *(const float4*)&sbuf[(g)&3][(mt*4+0)*256 + lane*4];    \
        const float4 q1 = *(const float4*)&sbuf[(g)&3][(mt*4+1)*256 + lane*4];    \
        const float4 q2 = *(const float4*)&sbuf[(g)&3][(mt*4+2)*256 + lane*4];    \
        const float4 q3 = *(const float4*)&sbuf[(g)&3][(mt*4+3)*256 + lane*4];    \
        const short8 xb0 = cvt8f(q0, q1);                                         \
        const short8 xb1 = cvt8f(q2, q3);                                         \
        floatx4 a0 = {0.f,0.f,0.f,0.f}, a1 = {0.f,0.f,0.f,0.f},                   \
                a2 = {0.f,0.f,0.f,0.f};                                           \
        a0 = __builtin_amdgcn_mfma_f32_16x16x32_bf16(wa[0][0], xb0, a0,0,0,0);    \
        a0 = __builtin_amdgcn_mfma_f32_16x16x32_bf16(wa[0][1], xb1, a0,0,0,0);    \
        a1 = __builtin_amdgcn_mfma_f32_16x16x32_bf16(wa[1][0], xb0, a1,0,0,0);    \
        a1 = __builtin_amdgcn_mfma_f32_16x16x32_bf16(wa[1][1], xb1, a1,0,0,0);    \
        a2 = __builtin_amdgcn_mfma_f32_16x16x32_bf16(wa[2][0], xb0, a2,0,0,0);    \
        a2 = __builtin_amdgcn_mfma_f32_16x16x32_bf16(wa[2][1], xb1, a2,0,0,0);    \
        const int m_ = mv[g][mt];                                                 \
        const floatx4 v_ = (m_ == 0) ? a0 : ((m_ == 1) ? a1 : a2);                \
        *(floatx4*)(out + (orig_ + mt * 16 + r15) * HID + wave * 16 + kg * 4)     \
            = v_;                                                                 \
    } } while (0)

// One iteration. Producer: issue stage(g+3) into buf (g-1)&3 (freed: B(g)
// proved COMPUTE(g-1) done), then wait stage(g+1) complete -- IN PARALLEL with
// consumers' COMPUTE(g). Barrier B(g+1) then publishes stage(g+1).
// Producer queue is stage-only: after STAGE(g+3), outstanding = tiles
// g+1,g+2,g+3 (48) -> wait tile g+1 done = vmcnt(32); edges 16, 0.
#define PITER(g, K)                                                               \
    if (prod) {                                                                   \
        if ((g) + 3 < GPB) { STAGE((g) + 3); SB; }                                \
        WAITV(K);                                                                 \
    } else {                                                                      \
        MODL((g) + 1); SB;                                                        \
        COMPUTE(g); SB;                                                           \
    }                                                                             \
    __builtin_amdgcn_s_barrier(); SB;

__global__ __launch_bounds__(BLOCK) void moe_pc(
    const float* __restrict__ x,
    const float* __restrict__ W,
    const int* __restrict__ mod,
    float* __restrict__ out)
{
    __shared__ float sbuf[NBUF][16 * 256];   // 4 x 16 KB = 64 KB

    const int tid  = threadIdx.x;
    const int wave = tid >> 6;               // 0..3 consumers, 4 producer
    const int lane = tid & 63;
    const int r15  = lane & 15;              // token within 16-group / MFMA col
    const int kg   = lane >> 4;              // k-group 0..3
    const bool prod = (wave == 4);

    const long blk0 = (long)blockIdx.x * (64 * GPB);

    int    mv[GPB][4];                       // static-indexed via unrolled macros
    short8 wa[3][2];

    // ---- prologue ----
    if (prod) {
        // fill the pipeline: 3 tiles (48 loads) in flight, wait tile 0 only
        STAGE(0); STAGE(1); STAGE(2); SB;
        WAITV(32);
    } else {
        // consumers: W fragments (their loads drain via cvt use) + mod tile 0
#pragma unroll
        for (int mm = 0; mm < 3; ++mm) {
            const float* wp = W + mm * 4096 + (wave * 16 + r15) * HID + kg * 8;
            wa[mm][0] = cvt8f(*(const float4*)wp,        *(const float4*)(wp + 4));
            wa[mm][1] = cvt8f(*(const float4*)(wp + 32), *(const float4*)(wp + 36));
        }
        MODL(0); SB;
    }
    __builtin_amdgcn_s_barrier(); SB;        // B(0): stage(0) published

    PITER(0, 32)
    PITER(1, 32)
    PITER(2, 32)
    PITER(3, 32)
    PITER(4, 32)
    PITER(5, 16)   // no stage(8): outstanding tiles 6,7 -> wait tile 6
    PITER(6, 0)    // outstanding tile 7 -> wait it (issued 2 iters ago)
    if (!prod) { COMPUTE(7); }
}

extern "C" void kernel_launch(void* const* d_in, const int* in_sizes, int n_in,
                              void* d_out, int out_size, void* d_ws, size_t ws_size,
                              hipStream_t stream) {
    const float* x   = (const float*)d_in[0];
    const float* W   = (const float*)d_in[1];
    const int*   mod = (const int*)d_in[2];
    float*       out = (float*)d_out;

    const int n      = in_sizes[0] / HID;     // tokens (1<<20)
    const int blocks = n / (64 * GPB);        // 2048

    moe_pc<<<blocks, BLOCK, 0, stream>>>(x, W, mod, out);
}

// Round 12
// 125.716 us; speedup vs baseline: 1.0400x; 1.0400x over previous
//
#include <hip/hip_runtime.h>
#include <hip/hip_bf16.h>

#define HID   64
#define BLOCK 256
#define TPT   32     // tokens per tile (8 KB)
#define GPB   8      // tiles per block -> 256 tokens/block -> 4096 blocks
#define NBUF  3      // triple buffer, 24 KB LDS -> ~5 blocks/CU

typedef short short8 __attribute__((ext_vector_type(8)));
typedef float floatx4 __attribute__((ext_vector_type(4)));

__device__ __forceinline__ short8 cvt8f(float4 f0, float4 f1) {
    union { __hip_bfloat162 h[4]; short8 s; } r;
    r.h[0] = __float22bfloat162_rn(make_float2(f0.x, f0.y));
    r.h[1] = __float22bfloat162_rn(make_float2(f0.z, f0.w));
    r.h[2] = __float22bfloat162_rn(make_float2(f1.x, f1.y));
    r.h[3] = __float22bfloat162_rn(make_float2(f1.z, f1.w));
    return r.s;
}

__device__ __forceinline__ void gload_lds16(const float* g, float* l) {
    __builtin_amdgcn_global_load_lds(
        (const __attribute__((address_space(1))) void*)g,
        (__attribute__((address_space(3))) void*)l, 16, 0, 0);
}

#define SB __builtin_amdgcn_sched_barrier(0)
#define WAITV(N) asm volatile("s_waitcnt vmcnt(" #N ")" ::: "memory")
#define BUF(g) ((g) % NBUF)

// Tile = 32 tokens = 8 chunks of 256 floats. Chunk c = mt*4 + kc*2 + hf holds,
// at 16B slot `lane`, x[orig + mt*16 + r15][kg*8 + kc*32 + hf*4 .. +4)
// (rule 21: pre-swizzled global src, linear LDS dest).
// Wave w stages chunks 2w, 2w+1 (mt = w>>1, kc = w&1, hf = 0/1): 2 loads/wave.
#define STAGE(g) do {                                                             \
    const long orig_ = blk0 + (g) * TPT;                                          \
    const float* s0_ = x + (orig_ + (wave >> 1) * 16 + r15) * HID                 \
                         + kg * 8 + (wave & 1) * 32;                              \
    gload_lds16(s0_,     &sbuf[BUF(g)][(wave * 2 + 0) * 256]);                    \
    gload_lds16(s0_ + 4, &sbuf[BUF(g)][(wave * 2 + 1) * 256]);                    \
    } while (0)

// mod loads for tile g's 2 token groups; ride the vmcnt queue at fixed slots.
#define MODL(g) do {                                                              \
    const long orig_ = blk0 + (g) * TPT;                                          \
    mv[g][0] = mod[orig_ + 0 * 16 + r15];                                         \
    mv[g][1] = mod[orig_ + 1 * 16 + r15];                                         \
    } while (0)

// Wave computes its 16 output cols (wave*16..) for the tile's 32 tokens.
#define COMPUTE(g) do {                                                           \
    const long orig_ = blk0 + (g) * TPT;                                          \
    _Pragma("unroll")                                                             \
    for (int mt = 0; mt < 2; ++mt) {                                              \
        const float4 q0 = *(const float4*)&sbuf[BUF(g)][(mt*4+0)*256 + lane*4];   \
        const float4 q1 = *(const float4*)&sbuf[BUF(g)][(mt*4+1)*256 + lane*4];   \
        const float4 q2 = *(const float4*)&sbuf[BUF(g)][(mt*4+2)*256 + lane*4];   \
        const float4 q3 = *(const float4*)&sbuf[BUF(g)][(mt*4+3)*256 + lane*4];   \
        const short8 xb0 = cvt8f(q0, q1);                                         \
        const short8 xb1 = cvt8f(q2, q3);                                         \
        floatx4 a0 = {0.f,0.f,0.f,0.f}, a1 = {0.f,0.f,0.f,0.f},                   \
                a2 = {0.f,0.f,0.f,0.f};                                           \
        a0 = __builtin_amdgcn_mfma_f32_16x16x32_bf16(wa[0][0], xb0, a0,0,0,0);    \
        a0 = __builtin_amdgcn_mfma_f32_16x16x32_bf16(wa[0][1], xb1, a0,0,0,0);    \
        a1 = __builtin_amdgcn_mfma_f32_16x16x32_bf16(wa[1][0], xb0, a1,0,0,0);    \
        a1 = __builtin_amdgcn_mfma_f32_16x16x32_bf16(wa[1][1], xb1, a1,0,0,0);    \
        a2 = __builtin_amdgcn_mfma_f32_16x16x32_bf16(wa[2][0], xb0, a2,0,0,0);    \
        a2 = __builtin_amdgcn_mfma_f32_16x16x32_bf16(wa[2][1], xb1, a2,0,0,0);    \
        const int m_ = mv[g][mt];                                                 \
        const floatx4 v_ = (m_ == 0) ? a0 : ((m_ == 1) ? a1 : a2);                \
        *(floatx4*)(out + (orig_ + mt * 16 + r15) * HID + wave * 16 + kg * 4)     \
            = v_;                                                                 \
    } } while (0)

// r9 skeleton: STAGE(g+2) -> counted WAIT(tile g staged) -> barrier ->
// COMPUTE(g) -> barrier (frees buf((g+2)%3) for the next iteration's stage).
#define ITER(g, K)                                                                \
    STAGE((g) + 2); SB; MODL((g) + 2); SB;                                        \
    WAITV(K); __builtin_amdgcn_s_barrier(); SB;                                   \
    COMPUTE(g); SB;                                                               \
    __builtin_amdgcn_s_barrier(); SB;

#define ITER_TAIL(g, K)                                                           \
    WAITV(K); __builtin_amdgcn_s_barrier(); SB;                                   \
    COMPUTE(g); SB;                                                               \
    __builtin_amdgcn_s_barrier(); SB;

__global__ __launch_bounds__(BLOCK) void moe_small(
    const float* __restrict__ x,
    const float* __restrict__ W,
    const int* __restrict__ mod,
    float* __restrict__ out)
{
    __shared__ float sbuf[NBUF][8 * 256];    // 3 x 8 KB = 24 KB

    const int tid  = threadIdx.x;
    const int wave = tid >> 6;               // 0..3
    const int lane = tid & 63;
    const int r15  = lane & 15;              // token within 16-group / MFMA col
    const int kg   = lane >> 4;              // k-group 0..3

    const long blk0 = (long)blockIdx.x * (TPT * GPB);

    int mv[GPB][2];                          // static-indexed via unrolled macros

    // ---- prologue: W fragments first (their loads drain via cvt use) ----
    short8 wa[3][2];
#pragma unroll
    for (int mm = 0; mm < 3; ++mm) {
        const float* wp = W + mm * 4096 + (wave * 16 + r15) * HID + kg * 8;
        wa[mm][0] = cvt8f(*(const float4*)wp,        *(const float4*)(wp + 4));
        wa[mm][1] = cvt8f(*(const float4*)(wp + 32), *(const float4*)(wp + 36));
    }
    SB;

    // queue: s0(2) m0(2) s1(2) m1(2)
    STAGE(0); SB; MODL(0); SB;
    STAGE(1); SB; MODL(1); SB;

    // exact counts (VMEM ops younger than tile g's last mod load):
    ITER(0, 8)    // s1m1(4) + s2m2(4) = 8
    ITER(1, 10)   // s2m2(4) + st0(2) + s3m3(4) = 10
    ITER(2, 12)   // st0(2)+s3m3(4)+st1(2)+s4m4(4) = 12
    ITER(3, 12) ITER(4, 12) ITER(5, 12)
    ITER_TAIL(6, 8)   // st4(2) + s7m7(4) + st5(2) = 8
    ITER_TAIL(7, 4)   // st5(2) + st6(2) = 4
}

extern "C" void kernel_launch(void* const* d_in, const int* in_sizes, int n_in,
                              void* d_out, int out_size, void* d_ws, size_t ws_size,
                              hipStream_t stream) {
    const float* x   = (const float*)d_in[0];
    const float* W   = (const float*)d_in[1];
    const int*   mod = (const int*)d_in[2];
    float*       out = (float*)d_out;

    const int n      = in_sizes[0] / HID;     // tokens (1<<20)
    const int blocks = n / (TPT * GPB);       // 4096

    moe_small<<<blocks, BLOCK, 0, stream>>>(x, W, mod, out);
}

// Round 13
// 117.755 us; speedup vs baseline: 1.1103x; 1.0676x over previous
//
#include <hip/hip_runtime.h>
#include <hip/hip_bf16.h>

#define HID   64
#define BLOCK 256
#define GPB   8      // 64-token tiles per block -> 2048 blocks
#define NBUF  3      // triple buffer, bf16 tiles: 3 x 8 KB = 24 KB

typedef short short8 __attribute__((ext_vector_type(8)));
typedef float floatx4 __attribute__((ext_vector_type(4)));

__device__ __forceinline__ short8 cvt8f(float4 f0, float4 f1) {
    union { __hip_bfloat162 h[4]; short8 s; } r;
    r.h[0] = __float22bfloat162_rn(make_float2(f0.x, f0.y));
    r.h[1] = __float22bfloat162_rn(make_float2(f0.z, f0.w));
    r.h[2] = __float22bfloat162_rn(make_float2(f1.x, f1.y));
    r.h[3] = __float22bfloat162_rn(make_float2(f1.z, f1.w));
    return r.s;
}

#define SB    __builtin_amdgcn_sched_barrier(0)
#define BAR   __builtin_amdgcn_s_barrier()
#define WAITV(N) asm volatile("s_waitcnt vmcnt(" #N ")" ::: "memory")
#define LGKM0    asm volatile("s_waitcnt lgkmcnt(0)" ::: "memory")

// Wave w stages tile-rows mt=w (16 tokens). Fragment-order global loads into
// regs (ping-pong by tile parity, all indices static): lane holds
// x[orig + w*16 + r15][kg*8 + {0,4,32,36} ..+4)
#define GLOAD(g) do {                                                             \
    const float* p_ = x + (blk0 + (g) * 64 + wave * 16 + r15) * (long)HID         \
                        + kg * 8;                                                 \
    xr##g[0] = *(const float4*)(p_);                                              \
    xr##g[1] = *(const float4*)(p_ + 4);                                          \
    xr##g[2] = *(const float4*)(p_ + 32);                                         \
    xr##g[3] = *(const float4*)(p_ + 36);                                         \
    } while (0)

// Convert tile g's staged regs to bf16 and write this wave's 2 chunks (2 KB).
// LDS layout: chunk (mt,kc) = sbuf[buf][mt*2+kc][lane][0..7]; slot holds bf16
// x[orig + mt*16 + (lane&15)][(lane>>4)*8 + kc*32 ..+8)  == MFMA B-fragment.
#define DSWRITE(g) do {                                                           \
    const short8 s0_ = cvt8f(xr##g[0], xr##g[1]);                                 \
    const short8 s1_ = cvt8f(xr##g[2], xr##g[3]);                                 \
    *(short8*)&sbuf[(g) % NBUF][wave * 2 + 0][lane][0] = s0_;                     \
    *(short8*)&sbuf[(g) % NBUF][wave * 2 + 1][lane][0] = s1_;                     \
    } while (0)

#define MODL(g) do {                                                              \
    const long orig_ = blk0 + (g) * 64;                                           \
    mv[g][0] = mod[orig_ +  0 + r15];                                             \
    mv[g][1] = mod[orig_ + 16 + r15];                                             \
    mv[g][2] = mod[orig_ + 32 + r15];                                             \
    mv[g][3] = mod[orig_ + 48 + r15];                                             \
    } while (0)

// Consumer: 8 ds_read_b128 (bf16 fragments direct to MFMA -- NO cvt), 24 MFMA,
// per-lane modality select, 4 line-complete dwordx4 stores.
#define COMPUTE(g) do {                                                           \
    const long orig_ = blk0 + (g) * 64;                                           \
    _Pragma("unroll")                                                             \
    for (int mt = 0; mt < 4; ++mt) {                                              \
        const short8 xb0 = *(const short8*)&sbuf[(g) % NBUF][mt*2+0][lane][0];    \
        const short8 xb1 = *(const short8*)&sbuf[(g) % NBUF][mt*2+1][lane][0];    \
        floatx4 a0 = {0.f,0.f,0.f,0.f}, a1 = {0.f,0.f,0.f,0.f},                   \
                a2 = {0.f,0.f,0.f,0.f};                                           \
        a0 = __builtin_amdgcn_mfma_f32_16x16x32_bf16(wa[0][0], xb0, a0,0,0,0);    \
        a0 = __builtin_amdgcn_mfma_f32_16x16x32_bf16(wa[0][1], xb1, a0,0,0,0);    \
        a1 = __builtin_amdgcn_mfma_f32_16x16x32_bf16(wa[1][0], xb0, a1,0,0,0);    \
        a1 = __builtin_amdgcn_mfma_f32_16x16x32_bf16(wa[1][1], xb1, a1,0,0,0);    \
        a2 = __builtin_amdgcn_mfma_f32_16x16x32_bf16(wa[2][0], xb0, a2,0,0,0);    \
        a2 = __builtin_amdgcn_mfma_f32_16x16x32_bf16(wa[2][1], xb1, a2,0,0,0);    \
        const int m_ = mv[g][mt];                                                 \
        const floatx4 v_ = (m_ == 0) ? a0 : ((m_ == 1) ? a1 : a2);                \
        *(floatx4*)(out + (orig_ + mt * 16 + r15) * HID + wave * 16 + kg * 4)     \
            = v_;                                                                 \
    } } while (0)

// r9 skeleton with reg-staged cvt: issue GL(g+2); wait GL(g+1) landed (counted,
// stores never gate); cvt+ds_write(g+1); barrier (publishes DSW(g)); compute(g);
// barrier (frees buf for DSW(g+2) overwrite, 3-buffer ring).
#define ITER(gp2, gp1, g, K)                                                      \
    GLOAD(gp2); MODL(gp2); SB;                                                    \
    WAITV(K); SB;                                                                 \
    DSWRITE(gp1); LGKM0;                                                          \
    BAR; SB;                                                                      \
    COMPUTE(g); SB;                                                               \
    BAR; SB;

__global__ __launch_bounds__(BLOCK) void moe_bflds(
    const float* __restrict__ x,
    const float* __restrict__ W,
    const int* __restrict__ mod,
    float* __restrict__ out)
{
    __shared__ short sbuf[NBUF][8][64][8];   // [buf][chunk][lane][8 bf16] = 24 KB

    const int tid  = threadIdx.x;
    const int wave = tid >> 6;               // 0..3
    const int lane = tid & 63;
    const int r15  = lane & 15;              // token within 16-group / MFMA col
    const int kg   = lane >> 4;              // k-group 0..3

    const long blk0 = (long)blockIdx.x * (64 * GPB);

    int    mv[GPB][4];                       // static-indexed (fully unrolled)
    float4 xr0[4], xr1[4], xr2[4], xr3[4], xr4[4], xr5[4], xr6[4], xr7[4];

    // ---- prologue: W fragments (loads drained by cvt use before staging) ----
    short8 wa[3][2];
#pragma unroll
    for (int mm = 0; mm < 3; ++mm) {
        const float* wp = W + mm * 4096 + (wave * 16 + r15) * HID + kg * 8;
        wa[mm][0] = cvt8f(*(const float4*)wp,        *(const float4*)(wp + 4));
        wa[mm][1] = cvt8f(*(const float4*)(wp + 32), *(const float4*)(wp + 36));
    }
    SB;

    // pipeline fill: queue = GL0(4) ML0(4) GL1(4) ML1(4)
    GLOAD(0); MODL(0); SB;
    GLOAD(1); MODL(1); SB;
    WAITV(12); SB;                 // GL0 done (younger: ML0? no -- ML0(4) GL1(4) ML1(4) = 12)
    DSWRITE(0); LGKM0; SB;

    // exact counts (VMEM younger than GL(g+1)'s last load):
    ITER(2, 1, 0, 12)   // ML1(4) + GL2(4) + ML2(4) = 12  (no stores yet)
    ITER(3, 2, 1, 16)   // ML2(4) + st0(4) + GL3(4) + ML3(4) = 16
    ITER(4, 3, 2, 16)
    ITER(5, 4, 3, 16)
    ITER(6, 5, 4, 16)
    ITER(7, 6, 5, 16)
    // tail: no GL(8)/ML(8)
    WAITV(8); SB;                  // GL7 done (younger: ML7(4) + st5(4) = 8)
    DSWRITE(7); LGKM0;
    BAR; SB;
    COMPUTE(6); SB;
    BAR; SB;
    COMPUTE(7);
}

extern "C" void kernel_launch(void* const* d_in, const int* in_sizes, int n_in,
                              void* d_out, int out_size, void* d_ws, size_t ws_size,
                              hipStream_t stream) {
    const float* x   = (const float*)d_in[0];
    const float* W   = (const float*)d_in[1];
    const int*   mod = (const int*)d_in[2];
    float*       out = (float*)d_out;

    const int n      = in_sizes[0] / HID;     // tokens (1<<20)
    const int blocks = n / (64 * GPB);        // 2048

    moe_bflds<<<blocks, BLOCK, 0, stream>>>(x, W, mod, out);
}

// Round 14
// 117.322 us; speedup vs baseline: 1.1144x; 1.0037x over previous
//
#include <hip/hip_runtime.h>
#include <hip/hip_bf16.h>

#define HID   64
#define BLOCK 256
#define GPB   8      // 64-token tiles per block -> 2048 blocks
#define NBUF  3      // triple buffer, bf16 tiles: 3 x 8 KB = 24 KB

typedef short short8 __attribute__((ext_vector_type(8)));
typedef float floatx4 __attribute__((ext_vector_type(4)));

__device__ __forceinline__ short8 cvt8f(float4 f0, float4 f1) {
    union { __hip_bfloat162 h[4]; short8 s; } r;
    r.h[0] = __float22bfloat162_rn(make_float2(f0.x, f0.y));
    r.h[1] = __float22bfloat162_rn(make_float2(f0.z, f0.w));
    r.h[2] = __float22bfloat162_rn(make_float2(f1.x, f1.y));
    r.h[3] = __float22bfloat162_rn(make_float2(f1.z, f1.w));
    return r.s;
}

#define SB    __builtin_amdgcn_sched_barrier(0)
#define BAR   __builtin_amdgcn_s_barrier()
#define WAITV(N) asm volatile("s_waitcnt vmcnt(" #N ")" ::: "memory")
#define LGKM0    asm volatile("s_waitcnt lgkmcnt(0)" ::: "memory")

// Wave w stages tile-rows mt=w (16 tokens). Fragment-order global loads into
// regs (ping-pong by tile parity, all indices static): lane holds
// x[orig + w*16 + r15][kg*8 + {0,4,32,36} ..+4)
#define GLOAD(g) do {                                                             \
    const float* p_ = x + (blk0 + (g) * 64 + wave * 16 + r15) * (long)HID         \
                        + kg * 8;                                                 \
    xr##g[0] = *(const float4*)(p_);                                              \
    xr##g[1] = *(const float4*)(p_ + 4);                                          \
    xr##g[2] = *(const float4*)(p_ + 32);                                         \
    xr##g[3] = *(const float4*)(p_ + 36);                                         \
    } while (0)

// Convert tile g's staged regs to bf16 and write this wave's 2 chunks (2 KB).
// LDS layout: chunk (mt,kc) = sbuf[buf][mt*2+kc][lane][0..7]; slot holds bf16
// x[orig + mt*16 + (lane&15)][(lane>>4)*8 + kc*32 ..+8)  == MFMA B-fragment.
#define DSWRITE(g) do {                                                           \
    const short8 s0_ = cvt8f(xr##g[0], xr##g[1]);                                 \
    const short8 s1_ = cvt8f(xr##g[2], xr##g[3]);                                 \
    *(short8*)&sbuf[(g) % NBUF][wave * 2 + 0][lane][0] = s0_;                     \
    *(short8*)&sbuf[(g) % NBUF][wave * 2 + 1][lane][0] = s1_;                     \
    } while (0)

#define MODL(g) do {                                                              \
    const long orig_ = blk0 + (g) * 64;                                           \
    mv[g][0] = mod[orig_ +  0 + r15];                                             \
    mv[g][1] = mod[orig_ + 16 + r15];                                             \
    mv[g][2] = mod[orig_ + 32 + r15];                                             \
    mv[g][3] = mod[orig_ + 48 + r15];                                             \
    } while (0)

// Consumer: 8 ds_read_b128 (bf16 fragments direct to MFMA -- NO cvt), 24 MFMA,
// per-lane modality select, 4 line-complete dwordx4 stores.
#define COMPUTE(g) do {                                                           \
    const long orig_ = blk0 + (g) * 64;                                           \
    _Pragma("unroll")                                                             \
    for (int mt = 0; mt < 4; ++mt) {                                              \
        const short8 xb0 = *(const short8*)&sbuf[(g) % NBUF][mt*2+0][lane][0];    \
        const short8 xb1 = *(const short8*)&sbuf[(g) % NBUF][mt*2+1][lane][0];    \
        floatx4 a0 = {0.f,0.f,0.f,0.f}, a1 = {0.f,0.f,0.f,0.f},                   \
                a2 = {0.f,0.f,0.f,0.f};                                           \
        a0 = __builtin_amdgcn_mfma_f32_16x16x32_bf16(wa[0][0], xb0, a0,0,0,0);    \
        a0 = __builtin_amdgcn_mfma_f32_16x16x32_bf16(wa[0][1], xb1, a0,0,0,0);    \
        a1 = __builtin_amdgcn_mfma_f32_16x16x32_bf16(wa[1][0], xb0, a1,0,0,0);    \
        a1 = __builtin_amdgcn_mfma_f32_16x16x32_bf16(wa[1][1], xb1, a1,0,0,0);    \
        a2 = __builtin_amdgcn_mfma_f32_16x16x32_bf16(wa[2][0], xb0, a2,0,0,0);    \
        a2 = __builtin_amdgcn_mfma_f32_16x16x32_bf16(wa[2][1], xb1, a2,0,0,0);    \
        const int m_ = mv[g][mt];                                                 \
        const floatx4 v_ = (m_ == 0) ? a0 : ((m_ == 1) ? a1 : a2);                \
        *(floatx4*)(out + (orig_ + mt * 16 + r15) * HID + wave * 16 + kg * 4)     \
            = v_;                                                                 \
    } } while (0)

// r9 skeleton with reg-staged cvt: issue GL(g+2); wait GL(g+1) landed (counted,
// stores never gate); cvt+ds_write(g+1); barrier (publishes DSW(g)); compute(g);
// barrier (frees buf for DSW(g+2) overwrite, 3-buffer ring).
#define ITER(gp2, gp1, g, K)                                                      \
    GLOAD(gp2); MODL(gp2); SB;                                                    \
    WAITV(K); SB;                                                                 \
    DSWRITE(gp1); LGKM0;                                                          \
    BAR; SB;                                                                      \
    COMPUTE(g); SB;                                                               \
    BAR; SB;

__global__ __launch_bounds__(BLOCK) void moe_bflds(
    const float* __restrict__ x,
    const float* __restrict__ W,
    const int* __restrict__ mod,
    float* __restrict__ out)
{
    __shared__ short sbuf[NBUF][8][64][8];   // [buf][chunk][lane][8 bf16] = 24 KB

    const int tid  = threadIdx.x;
    const int wave = tid >> 6;               // 0..3
    const int lane = tid & 63;
    const int r15  = lane & 15;              // token within 16-group / MFMA col
    const int kg   = lane >> 4;              // k-group 0..3

    const long blk0 = (long)blockIdx.x * (64 * GPB);

    int    mv[GPB][4];                       // static-indexed (fully unrolled)
    float4 xr0[4], xr1[4], xr2[4], xr3[4], xr4[4], xr5[4], xr6[4], xr7[4];

    // ---- prologue: W fragments (loads drained by cvt use before staging) ----
    short8 wa[3][2];
#pragma unroll
    for (int mm = 0; mm < 3; ++mm) {
        const float* wp = W + mm * 4096 + (wave * 16 + r15) * HID + kg * 8;
        wa[mm][0] = cvt8f(*(const float4*)wp,        *(const float4*)(wp + 4));
        wa[mm][1] = cvt8f(*(const float4*)(wp + 32), *(const float4*)(wp + 36));
    }
    SB;

    // pipeline fill: queue = GL0(4) ML0(4) GL1(4) ML1(4)
    GLOAD(0); MODL(0); SB;
    GLOAD(1); MODL(1); SB;
    WAITV(12); SB;                 // GL0 done (younger: ML0? no -- ML0(4) GL1(4) ML1(4) = 12)
    DSWRITE(0); LGKM0; SB;

    // exact counts (VMEM younger than GL(g+1)'s last load):
    ITER(2, 1, 0, 12)   // ML1(4) + GL2(4) + ML2(4) = 12  (no stores yet)
    ITER(3, 2, 1, 16)   // ML2(4) + st0(4) + GL3(4) + ML3(4) = 16
    ITER(4, 3, 2, 16)
    ITER(5, 4, 3, 16)
    ITER(6, 5, 4, 16)
    ITER(7, 6, 5, 16)
    // tail: no GL(8)/ML(8)
    WAITV(8); SB;                  // GL7 done (younger: ML7(4) + st5(4) = 8)
    DSWRITE(7); LGKM0;
    BAR; SB;
    COMPUTE(6); SB;
    BAR; SB;
    COMPUTE(7);
}

extern "C" void kernel_launch(void* const* d_in, const int* in_sizes, int n_in,
                              void* d_out, int out_size, void* d_ws, size_t ws_size,
                              hipStream_t stream) {
    const float* x   = (const float*)d_in[0];
    const float* W   = (const float*)d_in[1];
    const int*   mod = (const int*)d_in[2];
    float*       out = (float*)d_out;

    const int n      = in_sizes[0] / HID;     // tokens (1<<20)
    const int blocks = n / (64 * GPB);        // 2048

    moe_bflds<<<blocks, BLOCK, 0, stream>>>(x, W, mod, out);
}